// Round 1
// baseline (1547.425 us; speedup 1.0000x reference)
//
#include <hip/hip_runtime.h>
#include <hip/hip_bf16.h>

#define T_TOK 512
#define H_DIM 2048
#define I_DIM 1024
#define E_NUM 64
#define K_TOP 8
#define LDA   40   // LDS row stride in bf16 elems (32 + 8 pad -> 80B, 16B-aligned, breaks pow2 banks)
#define BK    32

typedef __attribute__((ext_vector_type(8))) short short8;
typedef __attribute__((ext_vector_type(4))) float f32x4;

__device__ __forceinline__ unsigned short f2bf(float f) {
  union { float f; unsigned u; } v; v.f = f;
  unsigned r = v.u + 0x7fffu + ((v.u >> 16) & 1u);   // RNE
  return (unsigned short)(r >> 16);
}

__device__ __forceinline__ short8 pack8(float4 a, float4 b) {
  short8 r;
  r[0] = (short)f2bf(a.x); r[1] = (short)f2bf(a.y);
  r[2] = (short)f2bf(a.z); r[3] = (short)f2bf(a.w);
  r[4] = (short)f2bf(b.x); r[5] = (short)f2bf(b.y);
  r[6] = (short)f2bf(b.z); r[7] = (short)f2bf(b.w);
  return r;
}

// ---------------- Gating: fp32 logits, top-8, softmax, scatter ----------------
__global__ __launch_bounds__(256) void k_gate(const float* __restrict__ x,
                                              const float* __restrict__ Wgate,
                                              int* __restrict__ counts,
                                              unsigned* __restrict__ list,
                                              float* __restrict__ probs) {
  __shared__ float xs[H_DIM];
  __shared__ float lg[E_NUM];
  const int t = blockIdx.x;
  for (int i = threadIdx.x; i < H_DIM; i += 256) xs[i] = x[(size_t)t * H_DIM + i];
  __syncthreads();
  const int wv = threadIdx.x >> 6, lane = threadIdx.x & 63;
  for (int e = wv * 16; e < wv * 16 + 16; ++e) {
    const float* w = Wgate + (size_t)e * H_DIM;
    float s = 0.f;
    for (int k = lane; k < H_DIM; k += 64) s += xs[k] * w[k];
#pragma unroll
    for (int off = 32; off; off >>= 1) s += __shfl_down(s, off);
    if (lane == 0) lg[e] = s;
  }
  __syncthreads();
  if (wv != 0) return;
  // wave 0: top-8 of 64 (tie-break: lower index first, matching lax.top_k)
  float cur = lg[lane];
  float topv[K_TOP]; int topi[K_TOP];
#pragma unroll
  for (int j = 0; j < K_TOP; ++j) {
    float bv = cur; int bi = lane;
#pragma unroll
    for (int off = 32; off; off >>= 1) {
      float ov = __shfl_xor(bv, off);
      int   oi = __shfl_xor(bi, off);
      if (ov > bv || (ov == bv && oi < bi)) { bv = ov; bi = oi; }
    }
    topv[j] = bv; topi[j] = bi;
    if (lane == bi) cur = -__builtin_inff();
  }
  if (lane == 0) {
    float m = topv[0], sum = 0.f, p[K_TOP];
#pragma unroll
    for (int j = 0; j < K_TOP; ++j) { p[j] = __expf(topv[j] - m); sum += p[j]; }
    const float inv = 1.f / sum;
#pragma unroll
    for (int j = 0; j < K_TOP; ++j) {
      const int e = topi[j];
      const int pos = atomicAdd(&counts[e], 1);
      list[e * T_TOK + pos] = (unsigned)(t * K_TOP + j);
      probs[t * K_TOP + j] = p[j] * inv;
    }
  }
}

// ------------- Expert gate/up GEMMs + SwiGLU + prob, act -> ws (bf16) -------------
// grid: (I_DIM/64, E_NUM). Block tile: M=128 tokens x N=64 i-vals, K=H.
// 4 waves in 2x2; wave tile 64x32; 16x16x32 bf16 MFMA.
__global__ __launch_bounds__(256) void k_gateup(const float* __restrict__ x,
                                                const float* __restrict__ Wg,
                                                const float* __restrict__ Wu,
                                                const int* __restrict__ counts,
                                                const unsigned* __restrict__ list,
                                                const float* __restrict__ probs,
                                                unsigned short* __restrict__ act) {
  const int e = blockIdx.y;
  const int n = counts[e];
  if (n <= 0) return;
  const int ic = blockIdx.x;                 // I-chunk of 64
  const int tid = threadIdx.x;
  const int lane = tid & 63, wv = tid >> 6;
  const int wm = (wv >> 1) * 64;             // wave M offset: 0 / 64
  const int wn = (wv & 1) * 32;              // wave N offset: 0 / 32
  const int fr = lane & 15, fq = lane >> 4;  // fragment row / quad

  __shared__ __align__(16) unsigned short As[128 * LDA];
  __shared__ __align__(16) unsigned short Bgs[64 * LDA];
  __shared__ __align__(16) unsigned short Bus[64 * LDA];
  __shared__ float    ptile[128];
  __shared__ unsigned etile[128];

  const int arow = tid >> 1, ahalf = tid & 1;   // A staging: 128 rows x 2 halves (16 floats)
  const int brow = tid >> 2, bq = tid & 3;      // B staging: 64 rows x 4 quarters (8 floats)
  const float* bgp = Wg + ((size_t)e * I_DIM + (size_t)ic * 64 + brow) * H_DIM + bq * 8;
  const float* bup = Wu + ((size_t)e * I_DIM + (size_t)ic * 64 + brow) * H_DIM + bq * 8;

  for (int m0 = 0; m0 < n; m0 += 128) {
    const int mt = min(128, n - m0);
    __syncthreads();                            // protect etile/ptile vs previous epilogue
    if (tid < 128) {
      if (tid < mt) {
        const unsigned ent = list[e * T_TOK + m0 + tid];
        etile[tid] = ent;
        ptile[tid] = probs[ent];
      } else { etile[tid] = 0u; ptile[tid] = 0.f; }
    }
    __syncthreads();
    const float* ap = (arow < mt)
        ? x + (size_t)(etile[arow] >> 3) * H_DIM + ahalf * 16 : (const float*)0;

    f32x4 accg[4][2], accu[4][2];
    const f32x4 zero = {0.f, 0.f, 0.f, 0.f};
#pragma unroll
    for (int mi = 0; mi < 4; ++mi)
#pragma unroll
      for (int ni = 0; ni < 2; ++ni) { accg[mi][ni] = zero; accu[mi][ni] = zero; }

    for (int kt = 0; kt < H_DIM / BK; ++kt) {
      const int k0 = kt * BK;
      float4 a0, a1, a2, a3;
      if (ap) {
        a0 = *(const float4*)(ap + k0);     a1 = *(const float4*)(ap + k0 + 4);
        a2 = *(const float4*)(ap + k0 + 8); a3 = *(const float4*)(ap + k0 + 12);
      } else {
        a0 = make_float4(0.f, 0.f, 0.f, 0.f); a1 = a0; a2 = a0; a3 = a0;
      }
      const float4 g0 = *(const float4*)(bgp + k0);
      const float4 g1 = *(const float4*)(bgp + k0 + 4);
      const float4 u0 = *(const float4*)(bup + k0);
      const float4 u1 = *(const float4*)(bup + k0 + 4);
      __syncthreads();                          // prev MFMA reads done before overwrite
      *(short8*)&As[arow * LDA + ahalf * 16]     = pack8(a0, a1);
      *(short8*)&As[arow * LDA + ahalf * 16 + 8] = pack8(a2, a3);
      *(short8*)&Bgs[brow * LDA + bq * 8] = pack8(g0, g1);
      *(short8*)&Bus[brow * LDA + bq * 8] = pack8(u0, u1);
      __syncthreads();
      short8 af[4], bgf[2], buf[2];
#pragma unroll
      for (int i = 0; i < 4; ++i)
        af[i] = *(const short8*)&As[(wm + i * 16 + fr) * LDA + fq * 8];
#pragma unroll
      for (int i = 0; i < 2; ++i) {
        bgf[i] = *(const short8*)&Bgs[(wn + i * 16 + fr) * LDA + fq * 8];
        buf[i] = *(const short8*)&Bus[(wn + i * 16 + fr) * LDA + fq * 8];
      }
#pragma unroll
      for (int mi = 0; mi < 4; ++mi)
#pragma unroll
        for (int ni = 0; ni < 2; ++ni) {
          accg[mi][ni] = __builtin_amdgcn_mfma_f32_16x16x32_bf16(af[mi], bgf[ni], accg[mi][ni], 0, 0, 0);
          accu[mi][ni] = __builtin_amdgcn_mfma_f32_16x16x32_bf16(af[mi], buf[ni], accu[mi][ni], 0, 0, 0);
        }
    }
    // epilogue: act = silu(g)*u*p, bf16 -> ws. C/D: row=fq*4+r (M), col=fr (N).
#pragma unroll
    for (int mi = 0; mi < 4; ++mi) {
#pragma unroll
      for (int r = 0; r < 4; ++r) {
        const int m = wm + mi * 16 + fq * 4 + r;
        if (m < mt) {
          const float p = ptile[m];
          const size_t base = (size_t)etile[m] * I_DIM + (size_t)ic * 64 + wn + fr;
#pragma unroll
          for (int ni = 0; ni < 2; ++ni) {
            const float g = accg[mi][ni][r];
            const float u = accu[mi][ni][r];
            const float s = g / (1.f + __expf(-g));
            act[base + ni * 16] = f2bf(s * u * p);
          }
        }
      }
    }
  }
}

// ------------- Expert down GEMM: out += act @ Wd^T (fp32 atomics) -------------
// grid: (H_DIM/64, E_NUM). Block tile: M=128 tokens x N=64 h-vals, K=I.
__global__ __launch_bounds__(256) void k_down(const float* __restrict__ Wd,
                                              const int* __restrict__ counts,
                                              const unsigned* __restrict__ list,
                                              const unsigned short* __restrict__ act,
                                              float* __restrict__ out) {
  const int e = blockIdx.y;
  const int n = counts[e];
  if (n <= 0) return;
  const int hc = blockIdx.x;                 // H-chunk of 64
  const int tid = threadIdx.x;
  const int lane = tid & 63, wv = tid >> 6;
  const int wm = (wv >> 1) * 64;
  const int wn = (wv & 1) * 32;
  const int fr = lane & 15, fq = lane >> 4;

  __shared__ __align__(16) unsigned short As[128 * LDA];
  __shared__ __align__(16) unsigned short Bs[64 * LDA];
  __shared__ unsigned etile[128];

  const int arow = tid >> 1, ahalf = tid & 1;
  const int brow = tid >> 2, bq = tid & 3;
  const float* bp = Wd + ((size_t)e * H_DIM + (size_t)hc * 64 + brow) * I_DIM + bq * 8;

  for (int m0 = 0; m0 < n; m0 += 128) {
    const int mt = min(128, n - m0);
    __syncthreads();
    if (tid < 128) etile[tid] = (tid < mt) ? list[e * T_TOK + m0 + tid] : 0u;
    __syncthreads();
    const unsigned short* ap = (arow < mt)
        ? act + (size_t)etile[arow] * I_DIM + ahalf * 16 : (const unsigned short*)0;

    f32x4 acc[4][2];
    const f32x4 zero = {0.f, 0.f, 0.f, 0.f};
#pragma unroll
    for (int mi = 0; mi < 4; ++mi)
#pragma unroll
      for (int ni = 0; ni < 2; ++ni) acc[mi][ni] = zero;

    for (int kt = 0; kt < I_DIM / BK; ++kt) {
      const int k0 = kt * BK;
      int4 av0, av1;
      if (ap) { av0 = *(const int4*)(ap + k0); av1 = *(const int4*)(ap + k0 + 8); }
      else    { av0 = make_int4(0, 0, 0, 0);   av1 = av0; }
      const float4 b0 = *(const float4*)(bp + k0);
      const float4 b1 = *(const float4*)(bp + k0 + 4);
      __syncthreads();
      *(int4*)&As[arow * LDA + ahalf * 16]     = av0;
      *(int4*)&As[arow * LDA + ahalf * 16 + 8] = av1;
      *(short8*)&Bs[brow * LDA + bq * 8] = pack8(b0, b1);
      __syncthreads();
      short8 af[4], bf[2];
#pragma unroll
      for (int i = 0; i < 4; ++i)
        af[i] = *(const short8*)&As[(wm + i * 16 + fr) * LDA + fq * 8];
#pragma unroll
      for (int i = 0; i < 2; ++i)
        bf[i] = *(const short8*)&Bs[(wn + i * 16 + fr) * LDA + fq * 8];
#pragma unroll
      for (int mi = 0; mi < 4; ++mi)
#pragma unroll
        for (int ni = 0; ni < 2; ++ni)
          acc[mi][ni] = __builtin_amdgcn_mfma_f32_16x16x32_bf16(af[mi], bf[ni], acc[mi][ni], 0, 0, 0);
    }
#pragma unroll
    for (int mi = 0; mi < 4; ++mi) {
#pragma unroll
      for (int r = 0; r < 4; ++r) {
        const int m = wm + mi * 16 + fq * 4 + r;
        if (m < mt) {
          const unsigned tok = etile[m] >> 3;
          float* op = out + (size_t)tok * H_DIM + (size_t)hc * 64 + wn + fr;
#pragma unroll
          for (int ni = 0; ni < 2; ++ni)
            atomicAdd(op + ni * 16, acc[mi][ni][r]);
        }
      }
    }
  }
}

extern "C" void kernel_launch(void* const* d_in, const int* in_sizes, int n_in,
                              void* d_out, int out_size, void* d_ws, size_t ws_size,
                              hipStream_t stream) {
  const float* x     = (const float*)d_in[0];   // [T, H]
  const float* Wg    = (const float*)d_in[1];   // [E, I, H]
  const float* Wu    = (const float*)d_in[2];   // [E, I, H]
  const float* Wd    = (const float*)d_in[3];   // [E, H, I]
  const float* Wgate = (const float*)d_in[4];   // [E, H]
  float* out = (float*)d_out;                   // [T, H] fp32

  char* ws = (char*)d_ws;
  int*      counts = (int*)ws;                                  // 64 * 4
  unsigned* list   = (unsigned*)(ws + 256);                     // 64 * 512 * 4
  float*    probs  = (float*)(ws + 256 + E_NUM * T_TOK * 4);    // 512 * 8 * 4
  unsigned short* act = (unsigned short*)(ws + (1u << 20));     // 4096 * 1024 * 2 = 8 MB

  hipMemsetAsync(counts, 0, E_NUM * sizeof(int), stream);
  hipMemsetAsync(out, 0, (size_t)out_size * sizeof(float), stream);

  k_gate<<<T_TOK, 256, 0, stream>>>(x, Wgate, counts, list, probs);
  k_gateup<<<dim3(I_DIM / 64, E_NUM), 256, 0, stream>>>(x, Wg, Wu, counts, list, probs, act);
  k_down<<<dim3(H_DIM / 64, E_NUM), 256, 0, stream>>>(Wd, counts, list, act, out);
}